// Round 6
// baseline (351.437 us; speedup 1.0000x reference)
//
#include <hip/hip_runtime.h>
#include <hip/hip_bf16.h>

// HopfieldEnergy: energy_i = -(logsumexp_j(2 * xn_i . an_j) - log M)/2 + 1.0
// M = N = 8192, K = 256. bf16-MFMA matmul + fused row exp-sum.
// *** INSTRUMENTATION ROUND: 5 ablation probes (REPS=3) launched to scratch
// so rocprof top-5 shows their counters; real path unchanged. ***

#define MROWS 8192
#define NROWS 8192
#define KDIM  256
#define BM    256
#define BN    64
#define NSPLIT 16
#define REPS  3

// 2*log2(e): xb holds (2*log2e)*x_n so exp(2*s) == exp2(acc) directly.
#define XSCALE 2.8853900817779268f

typedef __bf16 bf16x8 __attribute__((ext_vector_type(8)));
typedef float  f32x4  __attribute__((ext_vector_type(4)));

static __device__ __forceinline__ unsigned short f2bf(float f) {
    __hip_bfloat16 h = __float2bfloat16(f);
    union { __hip_bfloat16 h; unsigned short u; } c;
    c.h = h;
    return c.u;
}

__global__ void normalize_kernel(const float* __restrict__ x,
                                 const float* __restrict__ a,
                                 __hip_bfloat16* __restrict__ xb,
                                 __hip_bfloat16* __restrict__ ab) {
    const int lane = threadIdx.x & 63;
    const int gwave = (blockIdx.x * blockDim.x + threadIdx.x) >> 6;
    const bool is_x = gwave < MROWS;
    const int r = is_x ? gwave : gwave - MROWS;
    const float* src = (is_x ? x : a) + (size_t)r * KDIM;

    float4 v = reinterpret_cast<const float4*>(src)[lane];
    float ss = v.x * v.x + v.y * v.y + v.z * v.z + v.w * v.w;
    #pragma unroll
    for (int o = 32; o > 0; o >>= 1) ss += __shfl_xor(ss, o);

    const float inv = 1.0f / fmaxf(sqrtf(ss), 1e-12f);
    const float scale = is_x ? (XSCALE * inv) : inv;

    union { ushort4 u4; unsigned short us[4]; } pk;
    pk.us[0] = f2bf(v.x * scale);
    pk.us[1] = f2bf(v.y * scale);
    pk.us[2] = f2bf(v.z * scale);
    pk.us[3] = f2bf(v.w * scale);

    if (is_x) {
        reinterpret_cast<ushort4*>(xb + (size_t)r * KDIM)[lane] = pk.u4;
    } else {
        char* base = (char*)(ab + (size_t)r * KDIM);
        const int off = (lane * 8) ^ ((r & 7) << 4);  // pre-swizzle source side
        *reinterpret_cast<ushort4*>(base + off) = pk.u4;
    }
}

// Shared body for real kernel (V=0, REPS=1 -> partial) and probes.
// V flags: stage-in-loop, ds_read B, exp2, barrier.
template <int V, int NREP>
static __device__ __forceinline__ void expsum_body(
    const __hip_bfloat16* __restrict__ xb,
    const __hip_bfloat16* __restrict__ ab,
    float* __restrict__ outbuf) {
    constexpr bool DO_STAGE = (V == 0) || (V == 2) || (V == 3);
    constexpr bool DO_LDS   = (V == 0) || (V == 1) || (V == 3);
    constexpr bool DO_EXP   = (V == 0) || (V == 1) || (V == 2);
    constexpr bool DO_BAR   = (V != 4);

    __shared__ __attribute__((aligned(16))) char lds[2][BN * 512];

    const int tid = threadIdx.x;
    const int lane = tid & 63;
    const int w = tid >> 6;
    const int mbase = blockIdx.x * BM;
    const int jstart = blockIdx.y * (NROWS / NSPLIT);
    const int nsteps = (NROWS / NSPLIT) / BN;  // 8

    bf16x8 afrag[4][8];
    const int arow = mbase + w * 64 + (lane & 15);
    const int kb = (lane >> 4) * 8;
    #pragma unroll
    for (int f = 0; f < 4; ++f)
        #pragma unroll
        for (int ks = 0; ks < 8; ++ks)
            afrag[f][ks] = *reinterpret_cast<const bf16x8*>(
                xb + (size_t)(arow + f * 16) * KDIM + ks * 32 + kb);

    auto stage = [&](int buf, int j0) {
        const char* src = (const char*)ab + (size_t)j0 * 512;
        #pragma unroll
        for (int i = 0; i < 8; ++i) {
            const int chunk = w * 8 + i;  // 32 KB tile
            __builtin_amdgcn_global_load_lds(
                (const __attribute__((address_space(1))) void*)
                    (src + chunk * 1024 + lane * 16),
                (__attribute__((address_space(3))) void*)
                    (&lds[buf][chunk * 1024]),
                16, 0, 0);
        }
    };

    float rowsum[4][4];
    #pragma unroll
    for (int f = 0; f < 4; ++f)
        #pragma unroll
        for (int r = 0; r < 4; ++r) rowsum[f][r] = 0.f;

    const int cb = (lane >> 4) * 16;
    const int rl = lane & 15;

    stage(0, jstart);   // always: pins LDS alloc + provides data
    if (!DO_BAR) __syncthreads();  // V4: one-time drain only

    for (int rep = 0; rep < NREP; ++rep) {
        for (int step = 0; step < nsteps; ++step) {
            if (DO_BAR) __syncthreads();
            if (DO_STAGE && step + 1 < nsteps)
                stage((step + 1) & 1, jstart + (step + 1) * BN);
            const char* L = lds[DO_STAGE ? (step & 1) : 0];

            #pragma unroll
            for (int sub = 0; sub < 2; ++sub) {
                const int r0 = rl + sub * 32;
                const int r1 = r0 + 16;
                f32x4 acc[4][2];
                #pragma unroll
                for (int f = 0; f < 4; ++f) {
                    acc[f][0] = (f32x4){0.f, 0.f, 0.f, 0.f};
                    acc[f][1] = (f32x4){0.f, 0.f, 0.f, 0.f};
                }
                #pragma unroll
                for (int ks = 0; ks < 8; ++ks) {
                    bf16x8 b0, b1;
                    if (DO_LDS) {
                        const int bcol = ks * 64 + cb;
                        b0 = *reinterpret_cast<const bf16x8*>(
                            &L[r0 * 512 + (bcol ^ ((r0 & 7) << 4))]);
                        b1 = *reinterpret_cast<const bf16x8*>(
                            &L[r1 * 512 + (bcol ^ ((r1 & 7) << 4))]);
                    } else {
                        b0 = afrag[ks & 3][ks];       // register junk B
                        b1 = afrag[(ks + 1) & 3][ks];
                    }
                    #pragma unroll
                    for (int f = 0; f < 4; ++f)
                        acc[f][0] = __builtin_amdgcn_mfma_f32_16x16x32_bf16(
                            afrag[f][ks], b0, acc[f][0], 0, 0, 0);
                    #pragma unroll
                    for (int f = 0; f < 4; ++f)
                        acc[f][1] = __builtin_amdgcn_mfma_f32_16x16x32_bf16(
                            afrag[f][ks], b1, acc[f][1], 0, 0, 0);
                }
                // consume acc either way (no DCE, rule #17)
                #pragma unroll
                for (int f = 0; f < 4; ++f)
                    #pragma unroll
                    for (int g = 0; g < 2; ++g)
                        #pragma unroll
                        for (int r = 0; r < 4; ++r)
                            rowsum[f][r] += DO_EXP
                                ? __builtin_amdgcn_exp2f(acc[f][g][r])
                                : acc[f][g][r];
            }
        }
    }

    #pragma unroll
    for (int f = 0; f < 4; ++f)
        #pragma unroll
        for (int r = 0; r < 4; ++r) {
            float s = rowsum[f][r];
            s += __shfl_xor(s, 1);
            s += __shfl_xor(s, 2);
            s += __shfl_xor(s, 4);
            s += __shfl_xor(s, 8);
            rowsum[f][r] = s;
        }

    if ((lane & 15) == 0) {
        const int rbase = mbase + w * 64 + (lane >> 4) * 4;
        #pragma unroll
        for (int f = 0; f < 4; ++f)
            #pragma unroll
            for (int r = 0; r < 4; ++r)
                outbuf[(size_t)blockIdx.y * MROWS + rbase + f * 16 + r] =
                    rowsum[f][r];
    }
}

__global__ __launch_bounds__(256, 2) void expsum_kernel(
    const __hip_bfloat16* __restrict__ xb,
    const __hip_bfloat16* __restrict__ ab,
    float* __restrict__ partial) {
    expsum_body<0, 1>(xb, ab, partial);
}

template <int V>
__global__ __launch_bounds__(256, 2) void probe_kernel(
    const __hip_bfloat16* __restrict__ xb,
    const __hip_bfloat16* __restrict__ ab,
    float* __restrict__ scratch) {
    expsum_body<V, REPS>(xb, ab, scratch);
}

__global__ void finalize_kernel(const float* __restrict__ partial,
                                float* __restrict__ out) {
    const int i = blockIdx.x * blockDim.x + threadIdx.x;
    float s = 0.f;
    #pragma unroll
    for (int p = 0; p < NSPLIT; ++p) s += partial[(size_t)p * MROWS + i];
    out[i] = -0.5f * (logf(s) - logf((float)NROWS)) + 1.0f;
}

extern "C" void kernel_launch(void* const* d_in, const int* in_sizes, int n_in,
                              void* d_out, int out_size, void* d_ws, size_t ws_size,
                              hipStream_t stream) {
    const float* x = (const float*)d_in[0];
    const float* a = (const float*)d_in[1];
    float* out = (float*)d_out;

    char* ws = (char*)d_ws;
    size_t off = 0;
    __hip_bfloat16* xb = (__hip_bfloat16*)(ws + off); off += (size_t)MROWS * KDIM * 2;
    __hip_bfloat16* ab = (__hip_bfloat16*)(ws + off); off += (size_t)NROWS * KDIM * 2;
    float* partial     = (float*)(ws + off);          off += (size_t)NSPLIT * MROWS * 4;
    float* scratch     = (float*)(ws + off);          // probe garbage, 512 KiB

    const dim3 grid(MROWS / BM, NSPLIT);

    normalize_kernel<<<(2 * MROWS) / 4, 256, 0, stream>>>(x, a, xb, ab);

    // ablation probes (counters only; outputs unused)
    probe_kernel<0><<<grid, 256, 0, stream>>>(xb, ab, scratch);
    probe_kernel<1><<<grid, 256, 0, stream>>>(xb, ab, scratch);
    probe_kernel<2><<<grid, 256, 0, stream>>>(xb, ab, scratch);
    probe_kernel<3><<<grid, 256, 0, stream>>>(xb, ab, scratch);
    probe_kernel<4><<<grid, 256, 0, stream>>>(xb, ab, scratch);

    expsum_kernel<<<grid, 256, 0, stream>>>(xb, ab, partial);
    finalize_kernel<<<MROWS / 256, 256, 0, stream>>>(partial, out);
}

// Round 7
// 47.649 us; speedup vs baseline: 7.3755x; 7.3755x over previous
//
#include <hip/hip_runtime.h>
#include <hip/hip_bf16.h>

// HopfieldEnergy: energy_i = -(logsumexp_j(2 * xn_i . an_j) - log M)/2 + 1.0
// M = N = 8192, K = 256. bf16-MFMA matmul + fused row exp-sum.
// R6 ablation: all pipes hidden except MFMA+VALU, which were SERIALIZED
// (MfmaUtil 50 + VALUBusy 32 ~= 100% of wall). R7: dual accumulators +
// sched_group_barrier-pinned [2 DS][2 MFMA][4 VALU] interleave so the exp
// drain of sub t-1 issues in the MFMA pipe shadow of sub t.

#define MROWS 8192
#define NROWS 8192
#define KDIM  256
#define BM    256
#define BN    64
#define NSPLIT 16

// 2*log2(e): xb holds (2*log2e)*x_n so exp(2*s) == exp2(acc) directly.
#define XSCALE 2.8853900817779268f

typedef __bf16 bf16x8 __attribute__((ext_vector_type(8)));
typedef float  f32x4  __attribute__((ext_vector_type(4)));

static __device__ __forceinline__ unsigned short f2bf(float f) {
    __hip_bfloat16 h = __float2bfloat16(f);
    union { __hip_bfloat16 h; unsigned short u; } c;
    c.h = h;
    return c.u;
}

__global__ void normalize_kernel(const float* __restrict__ x,
                                 const float* __restrict__ a,
                                 __hip_bfloat16* __restrict__ xb,
                                 __hip_bfloat16* __restrict__ ab) {
    const int lane = threadIdx.x & 63;
    const int gwave = (blockIdx.x * blockDim.x + threadIdx.x) >> 6;
    const bool is_x = gwave < MROWS;
    const int r = is_x ? gwave : gwave - MROWS;
    const float* src = (is_x ? x : a) + (size_t)r * KDIM;

    float4 v = reinterpret_cast<const float4*>(src)[lane];
    float ss = v.x * v.x + v.y * v.y + v.z * v.z + v.w * v.w;
    #pragma unroll
    for (int o = 32; o > 0; o >>= 1) ss += __shfl_xor(ss, o);

    const float inv = 1.0f / fmaxf(sqrtf(ss), 1e-12f);
    const float scale = is_x ? (XSCALE * inv) : inv;

    union { ushort4 u4; unsigned short us[4]; } pk;
    pk.us[0] = f2bf(v.x * scale);
    pk.us[1] = f2bf(v.y * scale);
    pk.us[2] = f2bf(v.z * scale);
    pk.us[3] = f2bf(v.w * scale);

    if (is_x) {
        reinterpret_cast<ushort4*>(xb + (size_t)r * KDIM)[lane] = pk.u4;
    } else {
        char* base = (char*)(ab + (size_t)r * KDIM);
        const int off = (lane * 8) ^ ((r & 7) << 4);  // pre-swizzle source side
        *reinterpret_cast<ushort4*>(base + off) = pk.u4;
    }
}

// grid (MROWS/BM, NSPLIT), block 256 (4 waves, 2 blocks/CU). Wave owns 64
// rows (afrag in 128 regs). B tile (BN=64 a-rows) double-buffered in LDS.
// Per step: sub0 (cols 0-31) writes accA draining accB; sub1 writes accB
// draining accA. sched_group_barrier pins [2 DS][2 MFMA][4 VALU]x4 per ks.
__global__ __launch_bounds__(256, 2) void expsum_kernel(
    const __hip_bfloat16* __restrict__ xb,
    const __hip_bfloat16* __restrict__ ab,
    float* __restrict__ partial) {
    __shared__ __attribute__((aligned(16))) char lds[2][BN * 512];

    const int tid = threadIdx.x;
    const int lane = tid & 63;
    const int w = tid >> 6;
    const int mbase = blockIdx.x * BM;
    const int jstart = blockIdx.y * (NROWS / NSPLIT);
    const int nsteps = (NROWS / NSPLIT) / BN;  // 8

    bf16x8 afrag[4][8];
    const int arow = mbase + w * 64 + (lane & 15);
    const int kb = (lane >> 4) * 8;
    #pragma unroll
    for (int f = 0; f < 4; ++f)
        #pragma unroll
        for (int ks = 0; ks < 8; ++ks)
            afrag[f][ks] = *reinterpret_cast<const bf16x8*>(
                xb + (size_t)(arow + f * 16) * KDIM + ks * 32 + kb);

    auto stage = [&](int buf, int j0) {
        const char* src = (const char*)ab + (size_t)j0 * 512;
        #pragma unroll
        for (int i = 0; i < 8; ++i) {
            const int chunk = w * 8 + i;  // 32 KB tile
            __builtin_amdgcn_global_load_lds(
                (const __attribute__((address_space(1))) void*)
                    (src + chunk * 1024 + lane * 16),
                (__attribute__((address_space(3))) void*)
                    (&lds[buf][chunk * 1024]),
                16, 0, 0);
        }
    };

    float rowsum[4][4];
    #pragma unroll
    for (int f = 0; f < 4; ++f)
        #pragma unroll
        for (int r = 0; r < 4; ++r) rowsum[f][r] = 0.f;

    const int cb = (lane >> 4) * 16;
    const int rl = lane & 15;

    f32x4 accA[4][2], accB[4][2];
    #pragma unroll
    for (int f = 0; f < 4; ++f) {           // prime accB: its one bogus drain
        accB[f][0] = (f32x4){0.f, 0.f, 0.f, 0.f};  // adds exp2(0)*512 total
        accB[f][1] = (f32x4){0.f, 0.f, 0.f, 0.f};  // per row -> -512 in final
    }

    // One sub-step: zero ACCW; roll b0/b1 through 8 ks slots; 8 MFMAs/slot
    // into ACCW; drain 4 elems of ACCE/slot; SGB pins the interleave.
#define SUBSTEP(SUB, ACCW, ACCE)                                              \
    {                                                                         \
        _Pragma("unroll")                                                     \
        for (int f = 0; f < 4; ++f) {                                         \
            ACCW[f][0] = (f32x4){0.f, 0.f, 0.f, 0.f};                         \
            ACCW[f][1] = (f32x4){0.f, 0.f, 0.f, 0.f};                         \
        }                                                                     \
        const int r0_ = rl + SUB * 32;                                        \
        const int r1_ = r0_ + 16;                                             \
        bf16x8 b0 = *reinterpret_cast<const bf16x8*>(                         \
            &L[r0_ * 512 + (cb ^ ((r0_ & 7) << 4))]);                         \
        bf16x8 b1 = *reinterpret_cast<const bf16x8*>(                         \
            &L[r1_ * 512 + (cb ^ ((r1_ & 7) << 4))]);                         \
        _Pragma("unroll")                                                     \
        for (int ks = 0; ks < 8; ++ks) {                                      \
            bf16x8 nb0 = b0, nb1 = b1;                                        \
            if (ks < 7) {                                                     \
                const int bc = (ks + 1) * 64 + cb;                            \
                nb0 = *reinterpret_cast<const bf16x8*>(                       \
                    &L[r0_ * 512 + (bc ^ ((r0_ & 7) << 4))]);                 \
                nb1 = *reinterpret_cast<const bf16x8*>(                       \
                    &L[r1_ * 512 + (bc ^ ((r1_ & 7) << 4))]);                 \
            } else if (SUB == 0) {                                            \
                const int rr0 = rl + 32, rr1 = rl + 48;                       \
                nb0 = *reinterpret_cast<const bf16x8*>(                       \
                    &L[rr0 * 512 + (cb ^ ((rr0 & 7) << 4))]);                 \
                nb1 = *reinterpret_cast<const bf16x8*>(                       \
                    &L[rr1 * 512 + (cb ^ ((rr1 & 7) << 4))]);                 \
            }                                                                 \
            _Pragma("unroll")                                                 \
            for (int f = 0; f < 4; ++f)                                       \
                ACCW[f][0] = __builtin_amdgcn_mfma_f32_16x16x32_bf16(         \
                    afrag[f][ks], b0, ACCW[f][0], 0, 0, 0);                   \
            _Pragma("unroll")                                                 \
            for (int f = 0; f < 4; ++f)                                       \
                ACCW[f][1] = __builtin_amdgcn_mfma_f32_16x16x32_bf16(         \
                    afrag[f][ks], b1, ACCW[f][1], 0, 0, 0);                   \
            _Pragma("unroll")                                                 \
            for (int u = 0; u < 4; ++u) {                                     \
                const int e = ks * 4 + u;  /* f=e>>3, g=(e>>2)&1, r=e&3 */    \
                rowsum[e >> 3][e & 3] += __builtin_amdgcn_exp2f(              \
                    ACCE[e >> 3][(e >> 2) & 1][e & 3]);                       \
            }                                                                 \
            if (ks < 7 || SUB == 0)                                           \
                __builtin_amdgcn_sched_group_barrier(0x100, 2, 0);            \
            __builtin_amdgcn_sched_group_barrier(0x008, 2, 0);                \
            __builtin_amdgcn_sched_group_barrier(0x002, 4, 0);                \
            __builtin_amdgcn_sched_group_barrier(0x008, 2, 0);                \
            __builtin_amdgcn_sched_group_barrier(0x002, 4, 0);                \
            __builtin_amdgcn_sched_group_barrier(0x008, 2, 0);                \
            __builtin_amdgcn_sched_group_barrier(0x002, 4, 0);                \
            __builtin_amdgcn_sched_group_barrier(0x008, 2, 0);                \
            __builtin_amdgcn_sched_group_barrier(0x002, 4, 0);                \
            b0 = nb0;                                                         \
            b1 = nb1;                                                         \
        }                                                                     \
    }

    stage(0, jstart);

    for (int step = 0; step < nsteps; ++step) {
        __syncthreads();  // stage(step) drained; prev buf reads done
        if (step + 1 < nsteps) stage((step + 1) & 1, jstart + (step + 1) * BN);
        const char* L = lds[step & 1];
        SUBSTEP(0, accA, accB)
        SUBSTEP(1, accB, accA)
    }
#undef SUBSTEP

    // epilogue: drain the final accB
    #pragma unroll
    for (int e = 0; e < 32; ++e)
        rowsum[e >> 3][e & 3] +=
            __builtin_amdgcn_exp2f(accB[e >> 3][(e >> 2) & 1][e & 3]);

    // sum across the 16 lanes sharing (lane>>4)
    #pragma unroll
    for (int f = 0; f < 4; ++f)
        #pragma unroll
        for (int r = 0; r < 4; ++r) {
            float s = rowsum[f][r];
            s += __shfl_xor(s, 1);
            s += __shfl_xor(s, 2);
            s += __shfl_xor(s, 4);
            s += __shfl_xor(s, 8);
            rowsum[f][r] = s;
        }

    if ((lane & 15) == 0) {
        const int rbase = mbase + w * 64 + (lane >> 4) * 4;
        #pragma unroll
        for (int f = 0; f < 4; ++f)
            #pragma unroll
            for (int r = 0; r < 4; ++r)
                partial[(size_t)blockIdx.y * MROWS + rbase + f * 16 + r] = rowsum[f][r];
    }
}

__global__ void finalize_kernel(const float* __restrict__ partial,
                                float* __restrict__ out) {
    const int i = blockIdx.x * blockDim.x + threadIdx.x;
    float s = 0.f;
    #pragma unroll
    for (int p = 0; p < NSPLIT; ++p) s += partial[(size_t)p * MROWS + i];
    s -= 512.0f;  // remove the primed-accB drain (exp2(0) * 32 lanes * 16 splits)
    out[i] = -0.5f * (logf(s) - logf((float)NROWS)) + 1.0f;
}

extern "C" void kernel_launch(void* const* d_in, const int* in_sizes, int n_in,
                              void* d_out, int out_size, void* d_ws, size_t ws_size,
                              hipStream_t stream) {
    const float* x = (const float*)d_in[0];
    const float* a = (const float*)d_in[1];
    float* out = (float*)d_out;

    char* ws = (char*)d_ws;
    size_t off = 0;
    __hip_bfloat16* xb = (__hip_bfloat16*)(ws + off); off += (size_t)MROWS * KDIM * 2;
    __hip_bfloat16* ab = (__hip_bfloat16*)(ws + off); off += (size_t)NROWS * KDIM * 2;
    float* partial     = (float*)(ws + off);          // NSPLIT*MROWS*4 = 512 KiB

    normalize_kernel<<<(2 * MROWS) / 4, 256, 0, stream>>>(x, a, xb, ab);
    expsum_kernel<<<dim3(MROWS / BM, NSPLIT), 256, 0, stream>>>(xb, ab, partial);
    finalize_kernel<<<MROWS / 256, 256, 0, stream>>>(partial, out);
}

// Round 9
// 46.496 us; speedup vs baseline: 7.5585x; 1.0248x over previous
//
#include <hip/hip_runtime.h>
#include <hip/hip_bf16.h>

// HopfieldEnergy: energy_i = -(logsumexp_j(2 * xn_i . an_j) - log M)/2 + 1.0
// M = N = 8192, K = 256. bf16-MFMA matmul + fused row exp-sum.
// R6 ablation: memory fully hidden; 50% MfmaUtil even for pure-MFMA probe at
// 2 waves/SIMD. R9: same proven R5 skeleton, but 8 waves x 32 rows per block
// (512 thr, f=2, ~115 VGPR) -> 2 blocks/CU = 4 waves/SIMD to feed the pipe.

#define MROWS 8192
#define NROWS 8192
#define KDIM  256
#define BM    256
#define BN    64
#define NSPLIT 16

// 2*log2(e): xb holds (2*log2e)*x_n so exp(2*s) == exp2(acc) directly.
#define XSCALE 2.8853900817779268f

typedef __bf16 bf16x8 __attribute__((ext_vector_type(8)));
typedef float  f32x4  __attribute__((ext_vector_type(4)));

static __device__ __forceinline__ unsigned short f2bf(float f) {
    __hip_bfloat16 h = __float2bfloat16(f);
    union { __hip_bfloat16 h; unsigned short u; } c;
    c.h = h;
    return c.u;
}

// One wave per row. Rows [0,8192) = x, [8192,16384) = a.
// xb = (2*log2e)*x_n, linear. ab = a_n with each row's 16B chunks XOR-swizzled
// by ((j&7)<<4) so expsum can global_load_lds linearly and ds_read swizzled.
__global__ void normalize_kernel(const float* __restrict__ x,
                                 const float* __restrict__ a,
                                 __hip_bfloat16* __restrict__ xb,
                                 __hip_bfloat16* __restrict__ ab) {
    const int lane = threadIdx.x & 63;
    const int gwave = (blockIdx.x * blockDim.x + threadIdx.x) >> 6;
    const bool is_x = gwave < MROWS;
    const int r = is_x ? gwave : gwave - MROWS;
    const float* src = (is_x ? x : a) + (size_t)r * KDIM;

    float4 v = reinterpret_cast<const float4*>(src)[lane];
    float ss = v.x * v.x + v.y * v.y + v.z * v.z + v.w * v.w;
    #pragma unroll
    for (int o = 32; o > 0; o >>= 1) ss += __shfl_xor(ss, o);

    const float inv = 1.0f / fmaxf(sqrtf(ss), 1e-12f);
    const float scale = is_x ? (XSCALE * inv) : inv;

    union { ushort4 u4; unsigned short us[4]; } pk;
    pk.us[0] = f2bf(v.x * scale);
    pk.us[1] = f2bf(v.y * scale);
    pk.us[2] = f2bf(v.z * scale);
    pk.us[3] = f2bf(v.w * scale);

    if (is_x) {
        reinterpret_cast<ushort4*>(xb + (size_t)r * KDIM)[lane] = pk.u4;
    } else {
        char* base = (char*)(ab + (size_t)r * KDIM);
        const int off = (lane * 8) ^ ((r & 7) << 4);  // pre-swizzle source side
        *reinterpret_cast<ushort4*>(base + off) = pk.u4;
    }
}

// grid (MROWS/BM=32, NSPLIT=16) = 512 blocks, 512 threads (8 waves).
// Wave owns 32 rows (f=2, afrag 64 VGPR); ~115 VGPR total, cap 128 via
// __launch_bounds__(512,4) -> 2 blocks/CU = 16 waves/CU = 4 waves/SIMD.
// B tile (BN=64 a-rows, 32KB) double-buffered in LDS (128KB/CU) via
// global_load_lds (source pre-swizzled, LDS linear), swizzled conflict-free
// ds_read_b128. Same 1-barrier double-buffer skeleton as R3-R7 (5x proven).
__global__ __launch_bounds__(512, 4) void expsum_kernel(
    const __hip_bfloat16* __restrict__ xb,
    const __hip_bfloat16* __restrict__ ab,
    float* __restrict__ partial) {
    __shared__ __attribute__((aligned(16))) char lds[2][BN * 512];

    const int tid = threadIdx.x;
    const int lane = tid & 63;
    const int w = tid >> 6;          // 0..7
    const int mbase = blockIdx.x * BM;
    const int jstart = blockIdx.y * (NROWS / NSPLIT);
    const int nsteps = (NROWS / NSPLIT) / BN;  // 8

    // A fragments: lane holds row (lane&15), k chunk (lane>>4)*8 (+ks*32).
    bf16x8 afrag[2][8];
    const int arow = mbase + w * 32 + (lane & 15);
    const int kb = (lane >> 4) * 8;
    #pragma unroll
    for (int f = 0; f < 2; ++f)
        #pragma unroll
        for (int ks = 0; ks < 8; ++ks)
            afrag[f][ks] = *reinterpret_cast<const bf16x8*>(
                xb + (size_t)(arow + f * 16) * KDIM + ks * 32 + kb);

    auto stage = [&](int buf, int j0) {
        const char* src = (const char*)ab + (size_t)j0 * 512;
        #pragma unroll
        for (int i = 0; i < 4; ++i) {
            const int chunk = w * 4 + i;  // 32 chunks x 1 KB = 32 KB tile
            __builtin_amdgcn_global_load_lds(
                (const __attribute__((address_space(1))) void*)
                    (src + chunk * 1024 + lane * 16),
                (__attribute__((address_space(3))) void*)
                    (&lds[buf][chunk * 1024]),
                16, 0, 0);
        }
    };

    float rowsum[2][4] = {{0.f, 0.f, 0.f, 0.f}, {0.f, 0.f, 0.f, 0.f}};
    const int cb = (lane >> 4) * 16;  // byte col base within a k-group
    const int rl = lane & 15;

    stage(0, jstart);

    for (int step = 0; step < nsteps; ++step) {
        __syncthreads();  // drains vmcnt: stage(step) landed; prev reads done
        if (step + 1 < nsteps) stage((step + 1) & 1, jstart + (step + 1) * BN);
        const char* L = lds[step & 1];

        #pragma unroll
        for (int sub = 0; sub < 2; ++sub) {
            const int r0 = rl + sub * 32;
            const int r1 = r0 + 16;

            f32x4 acc[2][2];
            #pragma unroll
            for (int f = 0; f < 2; ++f) {
                acc[f][0] = (f32x4){0.f, 0.f, 0.f, 0.f};
                acc[f][1] = (f32x4){0.f, 0.f, 0.f, 0.f};
            }

            #pragma unroll
            for (int ks = 0; ks < 8; ++ks) {
                const int bcol = ks * 64 + cb;
                bf16x8 b0 = *reinterpret_cast<const bf16x8*>(
                    &L[r0 * 512 + (bcol ^ ((r0 & 7) << 4))]);
                bf16x8 b1 = *reinterpret_cast<const bf16x8*>(
                    &L[r1 * 512 + (bcol ^ ((r1 & 7) << 4))]);
                #pragma unroll
                for (int f = 0; f < 2; ++f) {
                    acc[f][0] = __builtin_amdgcn_mfma_f32_16x16x32_bf16(
                        afrag[f][ks], b0, acc[f][0], 0, 0, 0);
                    acc[f][1] = __builtin_amdgcn_mfma_f32_16x16x32_bf16(
                        afrag[f][ks], b1, acc[f][1], 0, 0, 0);
                }
            }

            // acc[f][g][r] = (2log2e)*s[row=f*16+(lane>>4)*4+r][col group]
            #pragma unroll
            for (int f = 0; f < 2; ++f)
                #pragma unroll
                for (int g = 0; g < 2; ++g)
                    #pragma unroll
                    for (int r = 0; r < 4; ++r)
                        rowsum[f][r] += __builtin_amdgcn_exp2f(acc[f][g][r]);
        }
    }

    // sum across the 16 lanes sharing (lane>>4)
    #pragma unroll
    for (int f = 0; f < 2; ++f)
        #pragma unroll
        for (int r = 0; r < 4; ++r) {
            float s = rowsum[f][r];
            s += __shfl_xor(s, 1);
            s += __shfl_xor(s, 2);
            s += __shfl_xor(s, 4);
            s += __shfl_xor(s, 8);
            rowsum[f][r] = s;
        }

    if ((lane & 15) == 0) {
        const int rbase = mbase + w * 32 + (lane >> 4) * 4;
        #pragma unroll
        for (int f = 0; f < 2; ++f)
            #pragma unroll
            for (int r = 0; r < 4; ++r)
                partial[(size_t)blockIdx.y * MROWS + rbase + f * 16 + r] = rowsum[f][r];
    }
}

__global__ void finalize_kernel(const float* __restrict__ partial,
                                float* __restrict__ out) {
    const int i = blockIdx.x * blockDim.x + threadIdx.x;
    float s = 0.f;
    #pragma unroll
    for (int p = 0; p < NSPLIT; ++p) s += partial[(size_t)p * MROWS + i];
    // energy = -(log(sum)-log M)/2 + 0.5||xn||^2 + 0.5 max||an||^2, norms == 1
    out[i] = -0.5f * (logf(s) - logf((float)NROWS)) + 1.0f;
}

extern "C" void kernel_launch(void* const* d_in, const int* in_sizes, int n_in,
                              void* d_out, int out_size, void* d_ws, size_t ws_size,
                              hipStream_t stream) {
    const float* x = (const float*)d_in[0];
    const float* a = (const float*)d_in[1];
    float* out = (float*)d_out;

    char* ws = (char*)d_ws;
    size_t off = 0;
    __hip_bfloat16* xb = (__hip_bfloat16*)(ws + off); off += (size_t)MROWS * KDIM * 2;  // 4 MiB
    __hip_bfloat16* ab = (__hip_bfloat16*)(ws + off); off += (size_t)NROWS * KDIM * 2;  // 4 MiB
    float* partial     = (float*)(ws + off);          // NSPLIT*MROWS*4 = 512 KiB

    normalize_kernel<<<(2 * MROWS) / 4, 256, 0, stream>>>(x, a, xb, ab);
    expsum_kernel<<<dim3(MROWS / BM, NSPLIT), 512, 0, stream>>>(xb, ab, partial);
    finalize_kernel<<<MROWS / 256, 256, 0, stream>>>(partial, out);
}